// Round 3
// baseline (70.574 us; speedup 1.0000x reference)
//
#include <hip/hip_runtime.h>

#define N_PTS   131072
// -log(1e-6)/32 : exact output when the sum clamps at 1e-6
#define FAR_CONST 0.4317347049363836f
// (0.907)^2. Vertices in [-0.15,0.15]^3 -> |v| <= 0.2599. |p| >= 0.907 =>
// d >= 0.647 per triangle => sum <= 256*exp(-32*(0.647-0.04)) = 9.4e-7 < 1e-6.
#define CUT2 0.8227f

// Planar triangle table: 34 arrays of 256 floats (lane-coalesced):
// f0..2 ba | f3 K1 | f4..6 cb | f7 K2 | f8..10 ac | f11 K3
// f12..14 c1/nsq | f15 Ks1 | f16..18 c2/nsq | f19 Ks2
// f20..22 nor/|n| | f23 Kun | f24..26 -2A | f27 |A|^2
// f28 basq f29 cbsq f30 acsq | f31..33 reciprocals

// ---- classify + compact (128 blocks x 1024); block 0 builds tri table -----
__global__ __launch_bounds__(1024) void classify_kernel(
    const float* __restrict__ p, const float* __restrict__ points,
    float* __restrict__ out, int* __restrict__ counter, int* __restrict__ cidx,
    float* __restrict__ cpx, float* __restrict__ cpy, float* __restrict__ cpz,
    float* __restrict__ tri)
{
    const int tid = threadIdx.x;

    if (blockIdx.x == 0 && tid < 256) {
        const int t = tid;
        const float* tp = points + t * 9;
        float Ax = tp[0], Ay = tp[1], Az = tp[2];
        float Bx = tp[3], By = tp[4], Bz = tp[5];
        float Cx = tp[6], Cy = tp[7], Cz = tp[8];

        float acx = Ax - Cx, acy = Ay - Cy, acz = Az - Cz;
        float bax = Bx - Ax, bay = By - Ay, baz = Bz - Az;
        float cbx = Cx - Bx, cby = Cy - By, cbz = Cz - Bz;

        float nx = bay * acz - baz * acy;
        float ny = baz * acx - bax * acz;
        float nz = bax * acy - bay * acx;
        float nsq = nx * nx + ny * ny + nz * nz;
        float inn = 1.0f / nsq;
        float rn  = sqrtf(inn);

        float c1x = bay * nz - baz * ny, c1y = baz * nx - bax * nz, c1z = bax * ny - bay * nx;
        float c2x = cby * nz - cbz * ny, c2y = cbz * nx - cbx * nz, c2z = cbx * ny - cby * nx;

        tri[ 0*256+t] = bax; tri[ 1*256+t] = bay; tri[ 2*256+t] = baz;
        tri[ 3*256+t] = -(bax * Ax + bay * Ay + baz * Az);
        tri[ 4*256+t] = cbx; tri[ 5*256+t] = cby; tri[ 6*256+t] = cbz;
        tri[ 7*256+t] = -(cbx * Bx + cby * By + cbz * Bz);
        tri[ 8*256+t] = acx; tri[ 9*256+t] = acy; tri[10*256+t] = acz;
        tri[11*256+t] = -(acx * Cx + acy * Cy + acz * Cz);
        tri[12*256+t] = c1x * inn; tri[13*256+t] = c1y * inn; tri[14*256+t] = c1z * inn;
        tri[15*256+t] = -(c1x * Ax + c1y * Ay + c1z * Az) * inn;
        tri[16*256+t] = c2x * inn; tri[17*256+t] = c2y * inn; tri[18*256+t] = c2z * inn;
        tri[19*256+t] = -(c2x * Bx + c2y * By + c2z * Bz) * inn;
        tri[20*256+t] = nx * rn; tri[21*256+t] = ny * rn; tri[22*256+t] = nz * rn;
        tri[23*256+t] = -(nx * Ax + ny * Ay + nz * Az) * rn;
        tri[24*256+t] = -2.0f * Ax; tri[25*256+t] = -2.0f * Ay; tri[26*256+t] = -2.0f * Az;
        tri[27*256+t] = Ax * Ax + Ay * Ay + Az * Az;
        float basq = bax * bax + bay * bay + baz * baz;
        float cbsq = cbx * cbx + cby * cby + cbz * cbz;
        float acsq = acx * acx + acy * acy + acz * acz;
        tri[28*256+t] = basq; tri[29*256+t] = cbsq; tri[30*256+t] = acsq;
        tri[31*256+t] = 1.0f / basq; tri[32*256+t] = 1.0f / cbsq; tri[33*256+t] = 1.0f / acsq;
    }

    const int i = blockIdx.x * 1024 + tid;
    const float px = p[3 * i + 0];
    const float py = p[3 * i + 1];
    const float pz = p[3 * i + 2];
    const float psq = fmaf(px, px, fmaf(py, py, pz * pz));

    out[i] = FAR_CONST;                        // near points overwritten later

    const bool near = psq < CUT2;
    const unsigned long long mask = __ballot(near);
    const int lane = tid & 63;
    const int wv   = tid >> 6;                 // 0..15

    __shared__ int wcnt[16];
    __shared__ int woff[16];
    __shared__ int sbase;
    if (lane == 0) wcnt[wv] = __popcll(mask);
    __syncthreads();
    if (tid == 0) {
        int tot = 0;
#pragma unroll
        for (int w = 0; w < 16; ++w) { woff[w] = tot; tot += wcnt[w]; }
        sbase = atomicAdd(counter, tot);       // ONE atomic per block
    }
    __syncthreads();

    if (near) {
        const int rank = __popcll(mask & ((1ull << lane) - 1));
        const int slot = sbase + woff[wv] + rank;
        cidx[slot] = i;
        cpx[slot] = px; cpy[slot] = py; cpz[slot] = pz;
    }
}

// DPP row-rotate-add helper (ctrl 0x120|n = row_ror:n)
template <int CTRL>
static __device__ __forceinline__ float row_ror_f(float x) {
    int r = __builtin_amdgcn_update_dpp(
        0, __builtin_bit_cast(int, x), CTRL, 0xF, 0xF, true);
    return __builtin_bit_cast(float, r);
}

// ---- main: 256 threads = 4 waves; lane l of wave w owns triangle w*64+l
// (constants in VGPRs). Loop over 32 compacted points (uniform s_load, 12 B/
// iter). Static grid; blocks past count exit. Tail lanes discarded at write.
//
// Cross-lane reduce is DPP-only (no DS, no permlane): after 4 row_ror adds,
// EVERY lane of a 16-lane row holds that row's 16-triangle partial sum. We
// never combine rows in-register: at iteration j, the 4 lanes (one per row)
// with lane&15 == j&15 keep their row partial -- into accA for j<16, accB
// for j>=16 (loop split so the choice is compile-time; rule: runtime-indexed
// acc goes to scratch). Epilogue sums 4 rows x 4 waves = 16 partials per
// point from LDS, once per block. Hot loop: zero DS ops; lgkm traffic is
// only the batched point s_loads.
__global__ __launch_bounds__(256, 4) void tri_main_kernel(
    const float* __restrict__ tri, const int* __restrict__ counter,
    const int* __restrict__ cidx,
    const float* __restrict__ cpx, const float* __restrict__ cpy,
    const float* __restrict__ cpz, float* __restrict__ out)
{
    const int count = *counter;                // uniform -> s_load
    const int gbase = blockIdx.x * 32;
    if (gbase >= count) return;

    __shared__ float red[4][2][64];            // [wave][jhalf][lane]

    const int tid  = threadIdx.x;
    const int lane = tid & 63;
    const int wv   = tid >> 6;
    const int l15  = lane & 15;
    const int t    = wv * 64 + lane;           // this lane's triangle

    const float ba_x = tri[ 0*256+t], ba_y = tri[ 1*256+t], ba_z = tri[ 2*256+t];
    const float K1   = tri[ 3*256+t];
    const float cb_x = tri[ 4*256+t], cb_y = tri[ 5*256+t], cb_z = tri[ 6*256+t];
    const float K2   = tri[ 7*256+t];
    const float ac_x = tri[ 8*256+t], ac_y = tri[ 9*256+t], ac_z = tri[10*256+t];
    const float K3   = tri[11*256+t];
    const float c1_x = tri[12*256+t], c1_y = tri[13*256+t], c1_z = tri[14*256+t];
    const float Ks1  = tri[15*256+t];
    const float c2_x = tri[16*256+t], c2_y = tri[17*256+t], c2_z = tri[18*256+t];
    const float Ks2  = tri[19*256+t];
    const float un_x = tri[20*256+t], un_y = tri[21*256+t], un_z = tri[22*256+t];
    const float Kun  = tri[23*256+t];
    const float mA_x = tri[24*256+t], mA_y = tri[25*256+t], mA_z = tri[26*256+t];
    const float KA   = tri[27*256+t];
    const float basq = tri[28*256+t], cbsq = tri[29*256+t], acsq = tri[30*256+t];
    const float ib   = tri[31*256+t], ic = tri[32*256+t], ia = tri[33*256+t];

    const float EK = -46.166241308446834f;     // -32*log2(e)
    const float EB = 1.8466496523378732f;      //  32*0.04*log2(e)

    float accA = 0.0f;                         // keeper for j in [0,16)
    float accB = 0.0f;                         // keeper for j in [16,32)

#define TRI_BODY(J, ACC)                                                      \
    {                                                                         \
        const int jj = (J);                                                   \
        const float px = cpx[gbase + jj];                                     \
        const float py = cpy[gbase + jj];                                     \
        const float pz = cpz[gbase + jj];                                     \
        const float psq = fmaf(px, px, fmaf(py, py, pz * pz));                \
                                                                              \
        float q1 = fmaf(ba_x, px, fmaf(ba_y, py, fmaf(ba_z, pz, K1)));        \
        float q2 = fmaf(cb_x, px, fmaf(cb_y, py, fmaf(cb_z, pz, K2)));        \
        float q3 = fmaf(ac_x, px, fmaf(ac_y, py, fmaf(ac_z, pz, K3)));        \
        float s1 = fmaf(c1_x, px, fmaf(c1_y, py, fmaf(c1_z, pz, Ks1)));       \
        float s2 = fmaf(c2_x, px, fmaf(c2_y, py, fmaf(c2_z, pz, Ks2)));       \
        float dn = fmaf(un_x, px, fmaf(un_y, py, fmaf(un_z, pz, Kun)));       \
                                                                              \
        float pasq = psq + fmaf(mA_x, px, fmaf(mA_y, py, fmaf(mA_z, pz, KA)));\
        float pbsq = fmaf(-2.0f, q1, pasq) + basq;                            \
        float pcsq = fmaf(-2.0f, q2, pbsq) + cbsq;                            \
                                                                              \
        float s3 = (1.0f - s1) - s2;                                          \
                                                                              \
        float t1 = __builtin_amdgcn_fmed3f(q1 * ib, 0.0f, 1.0f);              \
        float w1 = fmaf(-t1, basq, q1);                                       \
        float e1 = fmaf(-t1, q1 + w1, pasq);                                  \
                                                                              \
        float t2 = __builtin_amdgcn_fmed3f(q2 * ic, 0.0f, 1.0f);              \
        float w2 = fmaf(-t2, cbsq, q2);                                       \
        float e2 = fmaf(-t2, q2 + w2, pbsq);                                  \
                                                                              \
        float t3 = __builtin_amdgcn_fmed3f(q3 * ia, 0.0f, 1.0f);              \
        float w3 = fmaf(-t3, acsq, q3);                                       \
        float e3 = fmaf(-t3, q3 + w3, pcsq);                                  \
                                                                              \
        float same = fminf(fminf(e1, e2), e3);                                \
        float opp  = dn * dn;                                                 \
                                                                              \
        float mn  = fminf(fminf(s1, s2), s3);                                 \
        float med = __builtin_amdgcn_fmed3f(s1, s2, s3);                      \
        bool inside = (med > 0.0f) & (mn >= 0.0f);                            \
        float qv = inside ? opp : same;                                       \
                                                                              \
        float dd = __builtin_amdgcn_sqrtf(fmaxf(qv, 1e-8f));                  \
        float term = __builtin_amdgcn_exp2f(fmaf(dd, EK, EB));                \
                                                                              \
        /* row sum: after 4 ror adds every lane of the row holds the row's */ \
        /* 16-triangle partial */                                             \
        term += row_ror_f<0x121>(term);                                       \
        term += row_ror_f<0x122>(term);                                       \
        term += row_ror_f<0x124>(term);                                       \
        term += row_ror_f<0x128>(term);                                       \
        /* one lane per row keeps point jj's row partial */                   \
        ACC = (l15 == (jj & 15)) ? ACC + term : ACC;                          \
    }

#pragma unroll 4
    for (int j0 = 0; j0 < 16; ++j0)  TRI_BODY(j0, accA)
#pragma unroll 4
    for (int j1 = 16; j1 < 32; ++j1) TRI_BODY(j1, accB)
#undef TRI_BODY

    red[wv][0][lane] = accA;
    red[wv][1][lane] = accB;
    __syncthreads();

    if (tid < 32) {
        const int s = gbase + tid;
        if (s < count) {
            const int sel = tid >> 4;          // which acc held point tid
            const int col = tid & 15;
            float total = 0.0f;
#pragma unroll
            for (int w = 0; w < 4; ++w) {
                float rw = ((red[w][sel][ 0 + col] + red[w][sel][16 + col]) +
                            (red[w][sel][32 + col] + red[w][sel][48 + col]));
                total += rw;
            }
            out[cidx[s]] =
                -__builtin_amdgcn_logf(fmaxf(total, 1e-6f)) * 0.02166084939249829f;
        }
    }
}

extern "C" void kernel_launch(void* const* d_in, const int* in_sizes, int n_in,
                              void* d_out, int out_size, void* d_ws, size_t ws_size,
                              hipStream_t stream) {
    const float* p      = (const float*)d_in[0];
    const float* points = (const float*)d_in[1];
    float* out          = (float*)d_out;

    // ws: counter(2) | cidx[N] | cpx[N] | cpy[N] | cpz[N] | tri(34*256)
    int*   counter = (int*)d_ws;
    int*   cidx    = counter + 2;
    float* cpx     = (float*)(cidx + N_PTS);
    float* cpy     = cpx + N_PTS;
    float* cpz     = cpy + N_PTS;
    float* tri     = cpz + N_PTS;              // ~2.1 MB total

    (void)hipMemsetAsync(counter, 0, sizeof(int), stream);

    hipLaunchKernelGGL(classify_kernel, dim3(N_PTS / 1024), dim3(1024), 0, stream,
                       p, points, out, counter, cidx, cpx, cpy, cpz, tri);

    hipLaunchKernelGGL(tri_main_kernel, dim3(N_PTS / 32), dim3(256), 0, stream,
                       tri, counter, cidx, cpx, cpy, cpz, out);
}